// Round 1
// 18.890 us; speedup vs baseline: 1.1631x; 1.1631x over previous
//
#include <hip/hip_runtime.h>
#include <math.h>

// Problem constants (fixed shapes from setup_inputs)
#define B_N    16
#define T_LEN  65536
#define D_N    9                 // HARMONIC_NUM + 1
#define CHUNK  256
#define NCH    (T_LEN / CHUNK)   // 256 chunks per batch

#define RCP_SR (1.0f / 16000.0f)

#define AS1C(p) ((const __attribute__((address_space(1))) void*)(p))
#define AS3(p)  ((__attribute__((address_space(3))) void*)(p))

// ---------------------------------------------------------------------------
// Pass 1: per-(b,chunk) sum of rad_1 = f0 * (1/16000), double accumulate,
// stored as float frac. Only harmonic 1 is scanned; others are derived as
// integer multiples (frac-preserving).
// grid = 1024 blocks x 256 threads; each WAVE owns one chunk (4 t/lane).
// ---------------------------------------------------------------------------
__global__ __launch_bounds__(256) void k_chunksum(const float* __restrict__ f0,
                                                  float* __restrict__ csum) {
    int tid  = threadIdx.x;
    int lane = tid & 63;
    int wid  = tid >> 6;
    int chunk = blockIdx.x * 4 + wid;       // 0..4095 global chunk id
    int b = chunk >> 8;
    int c = chunk & 255;
    int t = c * CHUNK + lane * 4;
    size_t bt = (size_t)b * T_LEN + t;

    const float4 fv = *reinterpret_cast<const float4*>(f0 + bt);
    double s = (double)(fv.x * RCP_SR) + (double)(fv.y * RCP_SR)
             + (double)(fv.z * RCP_SR) + (double)(fv.w * RCP_SR);

    #pragma unroll
    for (int off = 32; off >= 1; off >>= 1)
        s += __shfl_down(s, off, 64);

    if (lane == 0) {
        double fr = s - floor(s);
        csum[(size_t)b * NCH + c] = (float)fr;
    }
}

// ---------------------------------------------------------------------------
// Pass 2 (fused): main kernel. Each WAVE owns one (b,chunk); lane owns 4
// consecutive timesteps.
//  - noise is staged global->LDS with 9 coalesced 1KB global_load_lds per
//    wave (linear LDS layout; the strided per-lane readback at
//    (9*lane+q)*16B has bank pattern 4(l+q)%32 == linear b128 -> conflict
//    free, no swizzle needed). Issued FIRST so HBM latency hides under the
//    phase scan + prefix computation.
//  - the old k_scan kernel is folded in: each wave computes its exclusive
//    chunk prefix from csum (coalesced 1KB read, L2-hit) with a masked
//    double sum + butterfly reduce.
// grid = 1024 blocks x 256 threads; LDS 36.9KB/block -> 4 blocks/CU.
// ---------------------------------------------------------------------------
__global__ __launch_bounds__(256, 4) void k_main(const float* __restrict__ f0,
                                                 const float* __restrict__ noise,
                                                 const float* __restrict__ W,
                                                 const float* __restrict__ bias,
                                                 const float* __restrict__ rinit,
                                                 const float* __restrict__ csum,
                                                 float* __restrict__ out) {
    __shared__ float4 ldsbuf[4 * 576];      // 4 waves x 576 granules = 36864 B
    int tid  = threadIdx.x;
    int lane = tid & 63;
    int wid  = tid >> 6;
    int chunk = blockIdx.x * 4 + wid;
    int b = chunk >> 8;
    int c = chunk & 255;
    int t = c * CHUNK + lane * 4;
    size_t bt = (size_t)b * T_LEN + t;

    // ---- issue coalesced noise -> LDS staging first (9 x 1KB per wave).
    // LDS dest is wave-uniform base + lane*16 (HW rule); global src is
    // per-lane. granule (q*64+lane) in LDS == global granule (lane+64q).
    float4* ldsw = ldsbuf + wid * 576;
    const float* nbase = noise + ((size_t)b * T_LEN + (size_t)c * CHUNK) * D_N;
    #pragma unroll
    for (int q = 0; q < 9; ++q) {
        const float* g = nbase + (size_t)(lane + 64 * q) * 4;
        __builtin_amdgcn_global_load_lds(AS1C(g), AS3(ldsw + q * 64), 16, 0, 0);
    }

    const float4 fv = *reinterpret_cast<const float4*>(f0 + bt);
    float f[4] = {fv.x, fv.y, fv.z, fv.w};

    // single (h=1) scan in double
    double s[4];
    double run = 0.0;
    #pragma unroll
    for (int j = 0; j < 4; ++j) {
        run += (double)(f[j] * RCP_SR);
        s[j] = run;
    }
    double incl = run;
    #pragma unroll
    for (int off = 1; off < 64; off <<= 1) {
        double n = __shfl_up(incl, off, 64);
        if (lane >= off) incl += n;
    }

    // ---- exclusive chunk prefix (replaces the old k_scan kernel):
    // lane l holds csum[b][4l..4l+3]; mask by global idx < c; butterfly sum.
    const float4 cs4 = *reinterpret_cast<const float4*>(csum + (size_t)b * NCH + lane * 4);
    int e0 = lane * 4;
    double pre = (e0 + 0 < c ? (double)cs4.x : 0.0)
               + (e0 + 1 < c ? (double)cs4.y : 0.0)
               + (e0 + 2 < c ? (double)cs4.z : 0.0)
               + (e0 + 3 < c ? (double)cs4.w : 0.0);
    #pragma unroll
    for (int off = 32; off >= 1; off >>= 1)
        pre += __shfl_xor(pre, off, 64);

    double base = (pre - floor(pre)) + (incl - run);

    // per-timestep fundamental phase in [0,1) as float
    float fr[4], uvf[4], na[4];
    #pragma unroll
    for (int j = 0; j < 4; ++j) {
        double qq = base + s[j];
        fr[j] = (float)(qq - floor(qq));
        bool uv = f[j] > 0.0f;
        uvf[j] = uv ? 0.1f : 0.0f;                   // fold SINE_AMP into uv
        na[j]  = uv ? 0.003f : (float)(0.1 / 3.0);   // NOISE_STD : SINE_AMP/3
    }

    // ---- wait for the LDS staging (wave-private region: no barrier needed)
    asm volatile("s_waitcnt vmcnt(0)" ::: "memory");

    // per-lane readback: granule (9*lane+q); bank pattern == linear b128.
    float nz[36];
    #pragma unroll
    for (int q = 0; q < 9; ++q) {
        float4 v4 = ldsw[9 * lane + q];
        nz[4 * q + 0] = v4.x; nz[4 * q + 1] = v4.y;
        nz[4 * q + 2] = v4.z; nz[4 * q + 3] = v4.w;
    }

    const float* ri = rinit + b * D_N;
    float acc[4] = {0.f, 0.f, 0.f, 0.f};

    #pragma unroll
    for (int h = 0; h < D_N; ++h) {
        const float hf = (float)(h + 1);
        const float wh = W[h];
        const float rih = ri[h];
        #pragma unroll
        for (int j = 0; j < 4; ++j) {
            float x  = fmaf(fr[j], hf, rih);               // phase*h + init
            float xf = __builtin_amdgcn_fractf(x);         // frac -> [0,1)
            float sn = __builtin_amdgcn_sinf(xf);          // sin(2*pi*xf)
            float sw = fmaf(na[j], nz[j * 9 + h], sn * uvf[j]);
            acc[j] = fmaf(sw, wh, acc[j]);
        }
    }

    // tanh(x) = 1 - 2/(exp(2x)+1)
    float bb = bias[0];
    float4 o;
    #pragma unroll
    for (int j = 0; j < 4; ++j) {
        float y = acc[j] + bb;
        float e = __expf(2.0f * y);
        float r = __builtin_amdgcn_rcpf(e + 1.0f);
        float th = 1.0f - 2.0f * r;
        (&o.x)[j] = th;
    }
    *reinterpret_cast<float4*>(out + bt) = o;
}

// ---------------------------------------------------------------------------
extern "C" void kernel_launch(void* const* d_in, const int* in_sizes, int n_in,
                              void* d_out, int out_size, void* d_ws, size_t ws_size,
                              hipStream_t stream) {
    const float* f0    = (const float*)d_in[0];
    const float* rinit = (const float*)d_in[1];
    const float* noise = (const float*)d_in[2];
    const float* W     = (const float*)d_in[3];
    const float* bias  = (const float*)d_in[4];
    float* out = (float*)d_out;

    // workspace: csum [16*256] f32
    float* csum = (float*)d_ws;

    k_chunksum<<<(B_N * NCH) / 4, 256, 0, stream>>>(f0, csum);
    k_main<<<(B_N * NCH) / 4, 256, 0, stream>>>(f0, noise, W, bias, rinit, csum, out);
}

// Round 3
// 17.910 us; speedup vs baseline: 1.2267x; 1.0547x over previous
//
#include <hip/hip_runtime.h>
#include <math.h>

// Problem constants (fixed shapes from setup_inputs)
#define B_N    16
#define T_LEN  65536
#define D_N    9                 // HARMONIC_NUM + 1
#define CHUNK  256
#define NCH    (T_LEN / CHUNK)   // 256 chunks per batch

#define RCP_SR (1.0f / 16000.0f)

#define AS1C(p) ((const __attribute__((address_space(1))) void*)(p))
#define AS3(p)  ((__attribute__((address_space(3))) void*)(p))

// ---------------------------------------------------------------------------
// Pass 1: per-(b,chunk) sum of rad_1 = f0 * (1/16000), double accumulate,
// stored as float frac. Only harmonic 1 is scanned; others are derived as
// integer multiples (frac-preserving).
// grid = 1024 blocks x 256 threads; each WAVE owns one chunk (4 t/lane).
// ---------------------------------------------------------------------------
__global__ __launch_bounds__(256) void k_chunksum(const float* __restrict__ f0,
                                                  float* __restrict__ csum) {
    int tid  = threadIdx.x;
    int lane = tid & 63;
    int wid  = tid >> 6;
    int chunk = blockIdx.x * 4 + wid;       // 0..4095 global chunk id
    int b = chunk >> 8;
    int c = chunk & 255;
    int t = c * CHUNK + lane * 4;
    size_t bt = (size_t)b * T_LEN + t;

    const float4 fv = *reinterpret_cast<const float4*>(f0 + bt);
    double s = (double)(fv.x * RCP_SR) + (double)(fv.y * RCP_SR)
             + (double)(fv.z * RCP_SR) + (double)(fv.w * RCP_SR);

    #pragma unroll
    for (int off = 32; off >= 1; off >>= 1)
        s += __shfl_down(s, off, 64);

    if (lane == 0) {
        double fr = s - floor(s);
        csum[(size_t)b * NCH + c] = (float)fr;
    }
}

// ---------------------------------------------------------------------------
// Pass 2 (fused main). Each WAVE owns one (b,chunk); lane owns 4 timesteps.
// KEY FIX vs previous round: vmcnt retires in ISSUE order, so the f0/csum
// loads must be issued BEFORE the 9 noise->LDS staging ops. Otherwise the
// compiler's wait for f0 (issued 10th) drains all 9 staging loads too and
// the scan gets zero overlap with the noise HBM latency. sched_barrier(0)
// pins the issue order. All phase math in float: chunk-local magnitudes
// are <= ~6.4 (prefix <= 256), error budget ~1e-4 rev << 5e-3 threshold.
// grid = 1024 blocks x 256 threads; LDS 36.9KB/block -> 4 blocks/CU.
// ---------------------------------------------------------------------------
__global__ __launch_bounds__(256, 4) void k_main(const float* __restrict__ f0,
                                                 const float* __restrict__ noise,
                                                 const float* __restrict__ W,
                                                 const float* __restrict__ bias,
                                                 const float* __restrict__ rinit,
                                                 const float* __restrict__ csum,
                                                 float* __restrict__ out) {
    __shared__ float4 ldsbuf[4 * 576];      // 4 waves x 576 granules = 36864 B
    int tid  = threadIdx.x;
    int lane = tid & 63;
    int wid  = tid >> 6;
    int chunk = blockIdx.x * 4 + wid;
    int b = chunk >> 8;
    int c = chunk & 255;
    int t = c * CHUNK + lane * 4;
    size_t bt = (size_t)b * T_LEN + t;

    // ---- issue the loads the PRE-WAIT compute depends on FIRST.
    const float4 fv  = *reinterpret_cast<const float4*>(f0 + bt);
    const float4 cs4 = *reinterpret_cast<const float4*>(csum + (size_t)b * NCH + lane * 4);

    // uniform operands -> scalar loads (readfirstlane makes b provably uniform)
    int bu = __builtin_amdgcn_readfirstlane(b);
    const float* ri = rinit + bu * D_N;
    float wreg[D_N], rireg[D_N];
    #pragma unroll
    for (int h = 0; h < D_N; ++h) { wreg[h] = W[h]; rireg[h] = ri[h]; }
    float bb = bias[0];

    __builtin_amdgcn_sched_barrier(0);

    // ---- noise -> LDS staging (9 x 1KB per wave), issued AFTER f0/csum.
    // LDS dest is wave-uniform base + lane*16 (HW rule); global src per-lane.
    // Per-lane readback at (9*lane+q)*16B has bank pattern 4(l+q)%32 ==
    // linear b128 -> conflict-free.
    float4* ldsw = ldsbuf + wid * 576;
    const float* nbase = noise + ((size_t)b * T_LEN + (size_t)c * CHUNK) * D_N;
    #pragma unroll
    for (int q = 0; q < 9; ++q) {
        const float* g = nbase + (size_t)(lane + 64 * q) * 4;
        __builtin_amdgcn_global_load_lds(AS1C(g), AS3(ldsw + q * 64), 16, 0, 0);
    }
    __builtin_amdgcn_sched_barrier(0);

    // ---- intra-wave scan of fundamental phase increment (float).
    float f[4] = {fv.x, fv.y, fv.z, fv.w};
    float s[4];
    float run = 0.0f;
    #pragma unroll
    for (int j = 0; j < 4; ++j) {
        run += f[j] * RCP_SR;
        s[j] = run;
    }
    float incl = run;
    #pragma unroll
    for (int off = 1; off < 64; off <<= 1) {
        float n = __shfl_up(incl, off, 64);
        if (lane >= off) incl += n;
    }

    // ---- exclusive chunk prefix: lane l holds csum[b][4l..4l+3],
    // mask by global idx < c, butterfly-sum (float, magnitude <= 256).
    int e0 = lane * 4;
    float pre = (e0 + 0 < c ? cs4.x : 0.0f)
              + (e0 + 1 < c ? cs4.y : 0.0f)
              + (e0 + 2 < c ? cs4.z : 0.0f)
              + (e0 + 3 < c ? cs4.w : 0.0f);
    #pragma unroll
    for (int off = 32; off >= 1; off >>= 1)
        pre += __shfl_xor(pre, off, 64);

    float base = __builtin_amdgcn_fractf(pre) + (incl - run);

    // per-timestep fundamental phase in [0,1), uv gates, noise amps.
    float fr[4], uvf[4], na[4];
    #pragma unroll
    for (int j = 0; j < 4; ++j) {
        fr[j] = __builtin_amdgcn_fractf(base + s[j]);   // base+s[j] <= ~8
        bool uv = f[j] > 0.0f;
        uvf[j] = uv ? 0.1f : 0.0f;                   // fold SINE_AMP into uv
        na[j]  = uv ? 0.003f : (float)(0.1 / 3.0);   // NOISE_STD : SINE_AMP/3
    }

    // ---- wait for noise staging (wave-private LDS region: no barrier).
    asm volatile("s_waitcnt vmcnt(0)" ::: "memory");

    // per-lane readback: granule (9*lane+q); bank pattern == linear b128.
    float nz[36];
    #pragma unroll
    for (int q = 0; q < 9; ++q) {
        float4 v4 = ldsw[9 * lane + q];
        nz[4 * q + 0] = v4.x; nz[4 * q + 1] = v4.y;
        nz[4 * q + 2] = v4.z; nz[4 * q + 3] = v4.w;
    }

    float acc[4] = {0.f, 0.f, 0.f, 0.f};
    #pragma unroll
    for (int h = 0; h < D_N; ++h) {
        const float hf = (float)(h + 1);
        const float wh = wreg[h];
        const float rih = rireg[h];
        #pragma unroll
        for (int j = 0; j < 4; ++j) {
            float x  = fmaf(fr[j], hf, rih);               // phase*h + init
            float xf = __builtin_amdgcn_fractf(x);         // frac -> [0,1)
            float sn = __builtin_amdgcn_sinf(xf);          // sin(2*pi*xf)
            float sw = fmaf(na[j], nz[j * 9 + h], sn * uvf[j]);
            acc[j] = fmaf(sw, wh, acc[j]);
        }
    }

    // tanh(x) = 1 - 2/(exp(2x)+1)
    float4 o;
    #pragma unroll
    for (int j = 0; j < 4; ++j) {
        float y = acc[j] + bb;
        float e = __expf(2.0f * y);
        float r = __builtin_amdgcn_rcpf(e + 1.0f);
        float th = 1.0f - 2.0f * r;
        (&o.x)[j] = th;
    }
    *reinterpret_cast<float4*>(out + bt) = o;
}

// ---------------------------------------------------------------------------
extern "C" void kernel_launch(void* const* d_in, const int* in_sizes, int n_in,
                              void* d_out, int out_size, void* d_ws, size_t ws_size,
                              hipStream_t stream) {
    const float* f0    = (const float*)d_in[0];
    const float* rinit = (const float*)d_in[1];
    const float* noise = (const float*)d_in[2];
    const float* W     = (const float*)d_in[3];
    const float* bias  = (const float*)d_in[4];
    float* out = (float*)d_out;

    // workspace: csum [16*256] f32
    float* csum = (float*)d_ws;

    k_chunksum<<<(B_N * NCH) / 4, 256, 0, stream>>>(f0, csum);
    k_main<<<(B_N * NCH) / 4, 256, 0, stream>>>(f0, noise, W, bias, rinit, csum, out);
}